// Round 2
// baseline (611.564 us; speedup 1.0000x reference)
//
#include <hip/hip_runtime.h>

typedef _Float16 half8 __attribute__((ext_vector_type(8)));
typedef float floatx4 __attribute__((ext_vector_type(4)));

#define MFMA16(A,B,C) __builtin_amdgcn_mfma_f32_16x16x32_f16((A),(B),(C),0,0,0)

// Problem constants (B=4, S=2048, D=1024, H=16, DPH=64)

// ---------------------------------------------------------------------------
// K0: bit-pack the int32 bool mask [B,S,S] -> u32 words [B,S,S/32]
// word w covers keys [w*32, w*32+32), bit k%32.
// ---------------------------------------------------------------------------
__global__ __launch_bounds__(256) void maskpack(
    const int* __restrict__ m, unsigned int* __restrict__ p)
{
  const int w = blockIdx.x * 256 + threadIdx.x;   // 524288 words total
  const int4* s = (const int4*)(m + (size_t)w * 32);
  unsigned int bits = 0;
#pragma unroll
  for (int j = 0; j < 8; ++j) {
    const int4 v = s[j];
    bits |= (v.x ? 1u : 0u) << (j * 4 + 0);
    bits |= (v.y ? 1u : 0u) << (j * 4 + 1);
    bits |= (v.z ? 1u : 0u) << (j * 4 + 2);
    bits |= (v.w ? 1u : 0u) << (j * 4 + 3);
  }
  p[w] = bits;
}

// ---------------------------------------------------------------------------
// K1: convert the 4 weight matrices fp32 [k][n] -> fp16 W^T [n][k]
// ---------------------------------------------------------------------------
__global__ __launch_bounds__(256) void wconv(
    const float* __restrict__ Wq, const float* __restrict__ Wk,
    const float* __restrict__ Wv, const float* __restrict__ Wo,
    _Float16* __restrict__ dst)
{
  const float* W = (blockIdx.z == 0) ? Wq : (blockIdx.z == 1) ? Wk
                  : (blockIdx.z == 2) ? Wv : Wo;
  _Float16* WT = dst + (size_t)blockIdx.z * 1024 * 1024;
  __shared__ float t[32][33];
  const int tx = threadIdx.x & 31;
  const int ty = threadIdx.x >> 5;
  const int k0 = blockIdx.x * 32, n0 = blockIdx.y * 32;
#pragma unroll
  for (int j = 0; j < 4; ++j)
    t[ty + j * 8][tx] = W[(size_t)(k0 + ty + j * 8) * 1024 + n0 + tx];
  __syncthreads();
#pragma unroll
  for (int j = 0; j < 4; ++j)
    WT[(size_t)(n0 + ty + j * 8) * 1024 + k0 + tx] = (_Float16)t[tx][ty + j * 8];
}

// ---------------------------------------------------------------------------
// K2/K4: GEMM C[8192,1024] = A[8192,1024] @ W + bias, fp16 MFMA, fp32 accum.
// OP 0: A=query fp32, out = half q_up [B,H,S,64], (acc+bias)*0.125
// OP 1: A=key   fp32, out = half k_up [B,H,S,64]
// OP 2: A=value fp32, out = half vT   [B,H,64,S]  (transposed per head)
// OP 3: A=ctx  fp16,  out = float d_out [8192,1024]
// Tile 128x128, BK=64, 4 waves (2x2 of 64x64), XOR-swizzled LDS.
// ---------------------------------------------------------------------------
template <int OP>
__global__ __launch_bounds__(256) void gemm_k(
    const void* __restrict__ Ap, const _Float16* __restrict__ BT,
    const float* __restrict__ bias, void* __restrict__ Cp)
{
  __shared__ __align__(16) _Float16 As[128 * 64];
  __shared__ __align__(16) _Float16 Bs[128 * 64];
  const int tid = threadIdx.x;
  const int lane = tid & 63;
  const int wv = tid >> 6;
  const int m0 = blockIdx.x * 128;
  const int n0 = blockIdx.y * 128;
  const int wr = (wv >> 1) * 64;
  const int wc = (wv & 1) * 64;

  floatx4 acc[4][4];
#pragma unroll
  for (int i = 0; i < 4; ++i)
#pragma unroll
    for (int j = 0; j < 4; ++j) acc[i][j] = (floatx4){0.f, 0.f, 0.f, 0.f};

  char* AsB = (char*)As;
  char* BsB = (char*)Bs;

  for (int ko = 0; ko < 1024; ko += 64) {
#pragma unroll
    for (int r = 0; r < 4; ++r) {
      const int idx = (r * 256 + tid) * 8;   // half index within 128x64 tile
      const int row = idx >> 6;
      const int colh = idx & 63;
      const int dstb = row * 128 + ((colh * 2) ^ ((row & 7) << 4));
      if (OP == 3) {
        const _Float16* s = (const _Float16*)Ap + (size_t)(m0 + row) * 1024 + ko + colh;
        *(half8*)(AsB + dstb) = *(const half8*)s;
      } else {
        const float* s = (const float*)Ap + (size_t)(m0 + row) * 1024 + ko + colh;
        floatx4 v0 = *(const floatx4*)s;
        floatx4 v1 = *(const floatx4*)(s + 4);
        half8 hv;
        hv[0] = (_Float16)v0[0]; hv[1] = (_Float16)v0[1];
        hv[2] = (_Float16)v0[2]; hv[3] = (_Float16)v0[3];
        hv[4] = (_Float16)v1[0]; hv[5] = (_Float16)v1[1];
        hv[6] = (_Float16)v1[2]; hv[7] = (_Float16)v1[3];
        *(half8*)(AsB + dstb) = hv;
      }
      const _Float16* bs = BT + (size_t)(n0 + row) * 1024 + ko + colh;
      *(half8*)(BsB + dstb) = *(const half8*)bs;
    }
    __syncthreads();
#pragma unroll
    for (int kk = 0; kk < 64; kk += 32) {
      half8 af[4], bf[4];
#pragma unroll
      for (int mi = 0; mi < 4; ++mi) {
        const int row = wr + mi * 16 + (lane & 15);
        const int cb = (kk + (lane >> 4) * 8) * 2;
        af[mi] = *(const half8*)(AsB + row * 128 + (cb ^ ((row & 7) << 4)));
      }
#pragma unroll
      for (int ni = 0; ni < 4; ++ni) {
        const int row = wc + ni * 16 + (lane & 15);
        const int cb = (kk + (lane >> 4) * 8) * 2;
        bf[ni] = *(const half8*)(BsB + row * 128 + (cb ^ ((row & 7) << 4)));
      }
#pragma unroll
      for (int mi = 0; mi < 4; ++mi)
#pragma unroll
        for (int ni = 0; ni < 4; ++ni)
          acc[mi][ni] = MFMA16(af[mi], bf[ni], acc[mi][ni]);
    }
    __syncthreads();
  }

  // Epilogue. C/D layout: col = lane&15, row = (lane>>4)*4 + i  (m89-verified)
#pragma unroll
  for (int ni = 0; ni < 4; ++ni) {
    const int nn = n0 + wc + ni * 16 + (lane & 15);
    const float bvv = bias[nn];
#pragma unroll
    for (int mi = 0; mi < 4; ++mi) {
      floatx4 c = acc[mi][ni];
#pragma unroll
      for (int i = 0; i < 4; ++i) {
        const int mm = m0 + wr + mi * 16 + (lane >> 4) * 4 + i;
        float val = c[i] + bvv;
        if (OP == 0) val *= 0.125f;   // 1/sqrt(DPH)
        if (OP == 0 || OP == 1) {
          _Float16* o = (_Float16*)Cp;
          const size_t off =
              ((size_t)((mm >> 11) * 16 + (nn >> 6)) * 2048 + (mm & 2047)) * 64 + (nn & 63);
          o[off] = (_Float16)val;
        } else if (OP == 2) {
          _Float16* o = (_Float16*)Cp;
          const size_t off =
              ((size_t)((mm >> 11) * 16 + (nn >> 6)) * 64 + (nn & 63)) * 2048 + (mm & 2047);
          o[off] = (_Float16)val;
        } else {
          float* o = (float*)Cp;
          o[(size_t)mm * 1024 + nn] = val;
        }
      }
    }
  }
}

// ---------------------------------------------------------------------------
// K3: flash attention. Grid (S/64, B*H). 4 waves; each wave owns 16 q-rows.
// KV step = 32 keys. Online softmax in fp32, P/V MFMA in fp16.
// mask bit set -> score = -1e30 (matches reference -1e18 semantics,
// including the all-masked -> uniform degenerate case).
// ---------------------------------------------------------------------------
__global__ __launch_bounds__(256) void attn_k(
    const _Float16* __restrict__ q_up, const _Float16* __restrict__ k_up,
    const _Float16* __restrict__ vT, const unsigned int* __restrict__ pmask,
    _Float16* __restrict__ ctx)
{
  const int tid = threadIdx.x;
  const int lane = tid & 63;
  const int wv = tid >> 6;
  const int bh = blockIdx.y;
  const int b = bh >> 4;
  const int h = bh & 15;
  const int qw = blockIdx.x * 64 + wv * 16;
  const int lr = lane & 15;
  const int lc = lane >> 4;

  const _Float16* qb = q_up + ((size_t)bh * 2048 + qw) * 64;
  const _Float16* kb = k_up + (size_t)bh * 2048 * 64;
  const _Float16* vb = vT + (size_t)bh * 64 * 2048;
  // packed mask row for this lane's 4 q-rows: [B,S,64 words]
  const unsigned int* mrow = pmask + ((size_t)b * 2048 + qw + lc * 4) * 64;

  __shared__ __align__(16) _Float16 P[4][16][40];

  const half8 qa0 = *(const half8*)(qb + lr * 64 + lc * 8);
  const half8 qa1 = *(const half8*)(qb + lr * 64 + 32 + lc * 8);

  floatx4 O[4];
#pragma unroll
  for (int dt = 0; dt < 4; ++dt) O[dt] = (floatx4){0.f, 0.f, 0.f, 0.f};
  float mr[4] = {-__builtin_inff(), -__builtin_inff(), -__builtin_inff(), -__builtin_inff()};
  float lsum[4] = {0.f, 0.f, 0.f, 0.f};

  for (int k0 = 0; k0 < 2048; k0 += 32) {
    // K fragments: B-frag lane holds col=key(lane&15), k=d contiguous 8
    const _Float16* kp = kb + (size_t)(k0 + lr) * 64 + lc * 8;
    const half8 kf00 = *(const half8*)kp;
    const half8 kf01 = *(const half8*)(kp + 32);
    const half8 kf10 = *(const half8*)(kp + 16 * 64);
    const half8 kf11 = *(const half8*)(kp + 16 * 64 + 32);
    floatx4 s0 = (floatx4){0.f, 0.f, 0.f, 0.f};
    floatx4 s1 = (floatx4){0.f, 0.f, 0.f, 0.f};
    s0 = MFMA16(qa0, kf00, s0);
    s0 = MFMA16(qa1, kf01, s0);
    s1 = MFMA16(qa0, kf10, s1);
    s1 = MFMA16(qa1, kf11, s1);

    const int wrd = k0 >> 5;
    // scores: row q = 4*lc + i, col key = k0 + {lr, 16+lr}
#pragma unroll
    for (int i = 0; i < 4; ++i) {
      const unsigned int mw = mrow[i * 64 + wrd];
      float a = s0[i], c = s1[i];
      if ((mw >> lr) & 1u) a = -1e30f;
      if ((mw >> (16 + lr)) & 1u) c = -1e30f;
      float tm = fmaxf(a, c);
      tm = fmaxf(tm, __shfl_xor(tm, 1));
      tm = fmaxf(tm, __shfl_xor(tm, 2));
      tm = fmaxf(tm, __shfl_xor(tm, 4));
      tm = fmaxf(tm, __shfl_xor(tm, 8));
      const float mn = fmaxf(mr[i], tm);
      const float alpha = __expf(mr[i] - mn);
      mr[i] = mn;
      const float e0 = __expf(a - mn);
      const float e1 = __expf(c - mn);
      float rs = e0 + e1;
      rs += __shfl_xor(rs, 1);
      rs += __shfl_xor(rs, 2);
      rs += __shfl_xor(rs, 4);
      rs += __shfl_xor(rs, 8);
      lsum[i] = lsum[i] * alpha + rs;
      O[0][i] *= alpha; O[1][i] *= alpha; O[2][i] *= alpha; O[3][i] *= alpha;
      P[wv][lc * 4 + i][lr] = (_Float16)e0;
      P[wv][lc * 4 + i][16 + lr] = (_Float16)e1;
    }
    // Re-layout P as PV A-frag: row q = lane&15, k = key = 8*(lane>>4)+j
    const half8 pa = *(const half8*)(&P[wv][lr][lc * 8]);
#pragma unroll
    for (int dt = 0; dt < 4; ++dt) {
      const _Float16* vp = vb + (size_t)(dt * 16 + lr) * 2048 + k0 + lc * 8;
      const half8 vf = *(const half8*)vp;
      O[dt] = MFMA16(pa, vf, O[dt]);
    }
  }

#pragma unroll
  for (int i = 0; i < 4; ++i) lsum[i] = 1.f / lsum[i];
#pragma unroll
  for (int dt = 0; dt < 4; ++dt) {
#pragma unroll
    for (int i = 0; i < 4; ++i) {
      const int qrow = qw + lc * 4 + i;
      ctx[((size_t)(b * 2048 + qrow)) * 1024 + (size_t)h * 64 + dt * 16 + lr] =
          (_Float16)(O[dt][i] * lsum[i]);
    }
  }
}

// ---------------------------------------------------------------------------
// Launch. Workspace layout (fp16 elements):
//   [0, 4M)     W^T for q,k,v,o (4 x 1024x1024)    8 MB
//   q_up  [B,H,S,64] 16 MB ; k_up 16 MB ; vT [B,H,64,S] 16 MB ; ctx 16 MB
//   pmask [B,S,64 u32 words] 2 MB
// Total ~74 MB.
// ---------------------------------------------------------------------------
extern "C" void kernel_launch(void* const* d_in, const int* in_sizes, int n_in,
                              void* d_out, int out_size, void* d_ws, size_t ws_size,
                              hipStream_t stream) {
  const float* key   = (const float*)d_in[0];
  const float* value = (const float*)d_in[1];
  const float* query = (const float*)d_in[2];
  const int*   mask  = (const int*)d_in[3];     // bool -> int32 per harness
  const float* Wq = (const float*)d_in[4];
  const float* bq = (const float*)d_in[5];
  const float* Wk = (const float*)d_in[6];
  const float* bk = (const float*)d_in[7];
  const float* Wv = (const float*)d_in[8];
  const float* bv = (const float*)d_in[9];
  const float* Wo = (const float*)d_in[10];
  const float* bo = (const float*)d_in[11];

  _Float16* wsp = (_Float16*)d_ws;
  _Float16* WT   = wsp;
  _Float16* q_up = wsp + (size_t)4 * 1024 * 1024;
  _Float16* k_up = q_up + (size_t)8192 * 1024;
  _Float16* vT   = k_up + (size_t)8192 * 1024;
  _Float16* ctx  = vT + (size_t)8192 * 1024;
  unsigned int* pmask = (unsigned int*)(ctx + (size_t)8192 * 1024);

  maskpack<<<dim3(2048), 256, 0, stream>>>(mask, pmask);
  wconv<<<dim3(32, 32, 4), 256, 0, stream>>>(Wq, Wk, Wv, Wo, WT);
  gemm_k<0><<<dim3(64, 8), 256, 0, stream>>>(query, WT, bq, q_up);
  gemm_k<1><<<dim3(64, 8), 256, 0, stream>>>(key, WT + (size_t)1024 * 1024, bk, k_up);
  gemm_k<2><<<dim3(64, 8), 256, 0, stream>>>(value, WT + (size_t)2 * 1024 * 1024, bv, vT);
  attn_k<<<dim3(32, 64), 256, 0, stream>>>(q_up, k_up, vT, pmask, ctx);
  gemm_k<3><<<dim3(64, 8), 256, 0, stream>>>(ctx, WT + (size_t)3 * 1024 * 1024, bo, (float*)d_out);
}

// Round 3
// 401.100 us; speedup vs baseline: 1.5247x; 1.5247x over previous
//
#include <hip/hip_runtime.h>

typedef _Float16 half8 __attribute__((ext_vector_type(8)));
typedef _Float16 half4 __attribute__((ext_vector_type(4)));
typedef float floatx4 __attribute__((ext_vector_type(4)));

#define MFMA16(A,B,C) __builtin_amdgcn_mfma_f32_16x16x32_f16((A),(B),(C),0,0,0)

// Problem constants (B=4, S=2048, D=1024, H=16, DPH=64)

// ---------------------------------------------------------------------------
// K0: bit-pack the int32 bool mask [B,S,S] -> u32 words [B,S,S/32]
// ---------------------------------------------------------------------------
__global__ __launch_bounds__(256) void maskpack(
    const int* __restrict__ m, unsigned int* __restrict__ p)
{
  const int w = blockIdx.x * 256 + threadIdx.x;   // 524288 words total
  const int4* s = (const int4*)(m + (size_t)w * 32);
  unsigned int bits = 0;
#pragma unroll
  for (int j = 0; j < 8; ++j) {
    const int4 v = s[j];
    bits |= (v.x ? 1u : 0u) << (j * 4 + 0);
    bits |= (v.y ? 1u : 0u) << (j * 4 + 1);
    bits |= (v.z ? 1u : 0u) << (j * 4 + 2);
    bits |= (v.w ? 1u : 0u) << (j * 4 + 3);
  }
  p[w] = bits;
}

// ---------------------------------------------------------------------------
// K1: convert the 4 weight matrices fp32 [k][n] -> fp16 W^T [n][k]
// ---------------------------------------------------------------------------
__global__ __launch_bounds__(256) void wconv(
    const float* __restrict__ Wq, const float* __restrict__ Wk,
    const float* __restrict__ Wv, const float* __restrict__ Wo,
    _Float16* __restrict__ dst)
{
  const float* W = (blockIdx.z == 0) ? Wq : (blockIdx.z == 1) ? Wk
                  : (blockIdx.z == 2) ? Wv : Wo;
  _Float16* WT = dst + (size_t)blockIdx.z * 1024 * 1024;
  __shared__ float t[32][33];
  const int tx = threadIdx.x & 31;
  const int ty = threadIdx.x >> 5;
  const int k0 = blockIdx.x * 32, n0 = blockIdx.y * 32;
#pragma unroll
  for (int j = 0; j < 4; ++j)
    t[ty + j * 8][tx] = W[(size_t)(k0 + ty + j * 8) * 1024 + n0 + tx];
  __syncthreads();
#pragma unroll
  for (int j = 0; j < 4; ++j)
    WT[(size_t)(n0 + ty + j * 8) * 1024 + k0 + tx] = (_Float16)t[tx][ty + j * 8];
}

// ---------------------------------------------------------------------------
// K2/K4: GEMM C[8192,1024] = A[8192,1024] @ W + bias, fp16 MFMA, fp32 accum.
// OP 0: A=query fp32, out = half q_up [B,H,S,64], (acc+bias)*0.125*log2(e)
// OP 1: A=key   fp32, out = half k_up [B,H,S,64]
// OP 2: A=value fp32, out = half vT   [B,H,64,S]  (transposed per head)
// OP 3: A=ctx  fp16,  out = float d_out [8192,1024]
// ---------------------------------------------------------------------------
template <int OP>
__global__ __launch_bounds__(256) void gemm_k(
    const void* __restrict__ Ap, const _Float16* __restrict__ BT,
    const float* __restrict__ bias, void* __restrict__ Cp)
{
  __shared__ __align__(16) _Float16 As[128 * 64];
  __shared__ __align__(16) _Float16 Bs[128 * 64];
  const int tid = threadIdx.x;
  const int lane = tid & 63;
  const int wv = tid >> 6;
  const int m0 = blockIdx.x * 128;
  const int n0 = blockIdx.y * 128;
  const int wr = (wv >> 1) * 64;
  const int wc = (wv & 1) * 64;

  floatx4 acc[4][4];
#pragma unroll
  for (int i = 0; i < 4; ++i)
#pragma unroll
    for (int j = 0; j < 4; ++j) acc[i][j] = (floatx4){0.f, 0.f, 0.f, 0.f};

  char* AsB = (char*)As;
  char* BsB = (char*)Bs;

  for (int ko = 0; ko < 1024; ko += 64) {
#pragma unroll
    for (int r = 0; r < 4; ++r) {
      const int idx = (r * 256 + tid) * 8;   // half index within 128x64 tile
      const int row = idx >> 6;
      const int colh = idx & 63;
      const int dstb = row * 128 + ((colh * 2) ^ ((row & 7) << 4));
      if (OP == 3) {
        const _Float16* s = (const _Float16*)Ap + (size_t)(m0 + row) * 1024 + ko + colh;
        *(half8*)(AsB + dstb) = *(const half8*)s;
      } else {
        const float* s = (const float*)Ap + (size_t)(m0 + row) * 1024 + ko + colh;
        floatx4 v0 = *(const floatx4*)s;
        floatx4 v1 = *(const floatx4*)(s + 4);
        half8 hv;
        hv[0] = (_Float16)v0[0]; hv[1] = (_Float16)v0[1];
        hv[2] = (_Float16)v0[2]; hv[3] = (_Float16)v0[3];
        hv[4] = (_Float16)v1[0]; hv[5] = (_Float16)v1[1];
        hv[6] = (_Float16)v1[2]; hv[7] = (_Float16)v1[3];
        *(half8*)(AsB + dstb) = hv;
      }
      const _Float16* bs = BT + (size_t)(n0 + row) * 1024 + ko + colh;
      *(half8*)(BsB + dstb) = *(const half8*)bs;
    }
    __syncthreads();
#pragma unroll
    for (int kk = 0; kk < 64; kk += 32) {
      half8 af[4], bf[4];
#pragma unroll
      for (int mi = 0; mi < 4; ++mi) {
        const int row = wr + mi * 16 + (lane & 15);
        const int cb = (kk + (lane >> 4) * 8) * 2;
        af[mi] = *(const half8*)(AsB + row * 128 + (cb ^ ((row & 7) << 4)));
      }
#pragma unroll
      for (int ni = 0; ni < 4; ++ni) {
        const int row = wc + ni * 16 + (lane & 15);
        const int cb = (kk + (lane >> 4) * 8) * 2;
        bf[ni] = *(const half8*)(BsB + row * 128 + (cb ^ ((row & 7) << 4)));
      }
#pragma unroll
      for (int mi = 0; mi < 4; ++mi)
#pragma unroll
        for (int ni = 0; ni < 4; ++ni)
          acc[mi][ni] = MFMA16(af[mi], bf[ni], acc[mi][ni]);
    }
    __syncthreads();
  }

  // Epilogue. C/D layout: col = lane&15, row = (lane>>4)*4 + i
#pragma unroll
  for (int ni = 0; ni < 4; ++ni) {
    const int nn = n0 + wc + ni * 16 + (lane & 15);
    const float bvv = bias[nn];
#pragma unroll
    for (int mi = 0; mi < 4; ++mi) {
      floatx4 c = acc[mi][ni];
#pragma unroll
      for (int i = 0; i < 4; ++i) {
        const int mm = m0 + wr + mi * 16 + (lane >> 4) * 4 + i;
        float val = c[i] + bvv;
        if (OP == 0) val *= 0.1803368801111204f;   // (1/8) * log2(e)
        if (OP == 0 || OP == 1) {
          _Float16* o = (_Float16*)Cp;
          const size_t off =
              ((size_t)((mm >> 11) * 16 + (nn >> 6)) * 2048 + (mm & 2047)) * 64 + (nn & 63);
          o[off] = (_Float16)val;
        } else if (OP == 2) {
          _Float16* o = (_Float16*)Cp;
          const size_t off =
              ((size_t)((mm >> 11) * 16 + (nn >> 6)) * 64 + (nn & 63)) * 2048 + (mm & 2047);
          o[off] = (_Float16)val;
        } else {
          float* o = (float*)Cp;
          o[(size_t)mm * 1024 + nn] = val;
        }
      }
    }
  }
}

// ---------------------------------------------------------------------------
// K3: flash attention, SWAPPED operands. Grid (S/128, B*H), 4 waves.
// Each wave owns 32 q-rows (2 q-tiles of 16), KV step = 64 keys.
// QK^T computed as mfma(K, Q): lane holds 16 scores for ONE q (col=lane&15),
// keys = 16*kt + 4*(lane>>4) + r. Softmax: in-lane reduce + 2 shuffles.
// PV swapped: O^T = mfma(V^T, P); P bounced through 2KB/wave swizzled LDS
// (wave-local, no barrier) to get key-contiguous B-fragments.
// Scores are in log2 domain (q_up pre-scaled by 0.125*log2e) -> native exp2.
// ---------------------------------------------------------------------------
__global__ __launch_bounds__(256) void attn_k(
    const _Float16* __restrict__ q_up, const _Float16* __restrict__ k_up,
    const _Float16* __restrict__ vT, const unsigned int* __restrict__ pmask,
    _Float16* __restrict__ ctx)
{
  const int tid = threadIdx.x;
  const int lane = tid & 63;
  const int wv = tid >> 6;
  const int bh = blockIdx.y;
  const int b = bh >> 4;
  const int h = bh & 15;
  const int qw = blockIdx.x * 128 + wv * 32;
  const int q16 = lane & 15;
  const int g = lane >> 4;

  __shared__ __align__(16) _Float16 Plds[4][2][16 * 64];   // 16 KB

  const _Float16* qb = q_up + ((size_t)bh * 2048 + qw) * 64;
  const _Float16* kb = k_up + (size_t)bh * 2048 * 64;
  const _Float16* vb = vT + (size_t)bh * 64 * 2048;
  const unsigned int* mrow = pmask + ((size_t)b * 2048 + qw + q16) * 64;

  // Q B-frags (hoisted): col=q16, k = ks*32 + 8g + j
  half8 qf[2][2];
#pragma unroll
  for (int qt = 0; qt < 2; ++qt)
#pragma unroll
    for (int ks = 0; ks < 2; ++ks)
      qf[qt][ks] = *(const half8*)(qb + (size_t)(qt * 16 + q16) * 64 + ks * 32 + g * 8);

  floatx4 O[2][4];
#pragma unroll
  for (int qt = 0; qt < 2; ++qt)
#pragma unroll
    for (int dt = 0; dt < 4; ++dt) O[qt][dt] = (floatx4){0.f, 0.f, 0.f, 0.f};
  float mr[2] = {-__builtin_inff(), -__builtin_inff()};
  float lsum[2] = {0.f, 0.f};

  char* Pb0 = (char*)&Plds[wv][0][0];
  char* Pb1 = (char*)&Plds[wv][1][0];
  const int swz = (q16 & 7) << 4;

  for (int k0 = 0; k0 < 2048; k0 += 64) {
    // K A-frags: row=key-in-tile=q16, k = ks*32 + 8g + j
    half8 kf[4][2];
#pragma unroll
    for (int kt = 0; kt < 4; ++kt)
#pragma unroll
      for (int ks = 0; ks < 2; ++ks)
        kf[kt][ks] = *(const half8*)(kb + (size_t)(k0 + kt * 16 + q16) * 64 + ks * 32 + g * 8);
    // V^T A-frags: row=d-in-tile=q16, k = kb2*32 + 8g + j (issued early to hide latency)
    half8 vf[4][2];
#pragma unroll
    for (int dt = 0; dt < 4; ++dt)
#pragma unroll
      for (int kb2 = 0; kb2 < 2; ++kb2)
        vf[dt][kb2] = *(const half8*)(vb + (size_t)(dt * 16 + q16) * 2048 + k0 + kb2 * 32 + g * 8);
    // mask words: 2 per q-tile
    unsigned int mw[2][2];
#pragma unroll
    for (int qt = 0; qt < 2; ++qt) {
      mw[qt][0] = mrow[qt * 1024 + (k0 >> 5)];
      mw[qt][1] = mrow[qt * 1024 + (k0 >> 5) + 1];
    }

    // QK^T: s[qt][kt][r] = score(q=qw+16qt+q16, key=k0+16kt+4g+r), log2 domain
    floatx4 s[2][4];
#pragma unroll
    for (int qt = 0; qt < 2; ++qt)
#pragma unroll
      for (int kt = 0; kt < 4; ++kt) {
        floatx4 acc0 = (floatx4){0.f, 0.f, 0.f, 0.f};
        acc0 = MFMA16(kf[kt][0], qf[qt][0], acc0);
        s[qt][kt] = MFMA16(kf[kt][1], qf[qt][1], acc0);
      }

#pragma unroll
    for (int qt = 0; qt < 2; ++qt) {
      // mask
#pragma unroll
      for (int kt = 0; kt < 4; ++kt) {
        const unsigned int w = mw[qt][kt >> 1] >> ((kt & 1) * 16 + 4 * g);
#pragma unroll
        for (int r = 0; r < 4; ++r)
          if ((w >> r) & 1u) s[qt][kt][r] = -1e30f;
      }
      // row max: 15 in-lane + 2 shuffles
      float pm = s[qt][0][0];
#pragma unroll
      for (int kt = 0; kt < 4; ++kt)
#pragma unroll
        for (int r = 0; r < 4; ++r) pm = fmaxf(pm, s[qt][kt][r]);
      pm = fmaxf(pm, __shfl_xor(pm, 16));
      pm = fmaxf(pm, __shfl_xor(pm, 32));
      const float mn = fmaxf(mr[qt], pm);
      const float alpha = __builtin_amdgcn_exp2f(mr[qt] - mn);
      mr[qt] = mn;
      // exp2 + row sum
      float rs = 0.f;
#pragma unroll
      for (int kt = 0; kt < 4; ++kt)
#pragma unroll
        for (int r = 0; r < 4; ++r) {
          const float e = __builtin_amdgcn_exp2f(s[qt][kt][r] - mn);
          s[qt][kt][r] = e;
          rs += e;
        }
      rs += __shfl_xor(rs, 16);
      rs += __shfl_xor(rs, 32);
      lsum[qt] = lsum[qt] * alpha + rs;
#pragma unroll
      for (int dt = 0; dt < 4; ++dt) O[qt][dt] *= alpha;
      // P -> LDS (fp16) at [q16][16*kt+4g..+3], XOR-swizzled
      char* Pb = qt ? Pb1 : Pb0;
#pragma unroll
      for (int kt = 0; kt < 4; ++kt) {
        half4 w4;
        w4[0] = (_Float16)s[qt][kt][0]; w4[1] = (_Float16)s[qt][kt][1];
        w4[2] = (_Float16)s[qt][kt][2]; w4[3] = (_Float16)s[qt][kt][3];
        *(half4*)(Pb + q16 * 128 + ((32 * kt + 8 * g) ^ swz)) = w4;
      }
    }

    // PV (wave-local LDS read-back, key-contiguous): B col=q16, k=32*kb2+8g+j
#pragma unroll
    for (int qt = 0; qt < 2; ++qt) {
      char* Pb = qt ? Pb1 : Pb0;
      half8 pb[2];
#pragma unroll
      for (int kb2 = 0; kb2 < 2; ++kb2)
        pb[kb2] = *(const half8*)(Pb + q16 * 128 + ((64 * kb2 + 16 * g) ^ swz));
#pragma unroll
      for (int dt = 0; dt < 4; ++dt) {
        O[qt][dt] = MFMA16(vf[dt][0], pb[0], O[qt][dt]);
        O[qt][dt] = MFMA16(vf[dt][1], pb[1], O[qt][dt]);
      }
    }
  }

  // Epilogue: O^T layout col=q16, row d = dt*16 + 4g + r. Normalize, pack 8B.
#pragma unroll
  for (int qt = 0; qt < 2; ++qt) {
    const float inv = 1.f / lsum[qt];
    const size_t rowb = ((size_t)(b * 2048 + qw + qt * 16 + q16)) * 1024 + h * 64;
#pragma unroll
    for (int dt = 0; dt < 4; ++dt) {
      half4 w4;
      w4[0] = (_Float16)(O[qt][dt][0] * inv);
      w4[1] = (_Float16)(O[qt][dt][1] * inv);
      w4[2] = (_Float16)(O[qt][dt][2] * inv);
      w4[3] = (_Float16)(O[qt][dt][3] * inv);
      *(half4*)(ctx + rowb + dt * 16 + 4 * g) = w4;
    }
  }
}

// ---------------------------------------------------------------------------
// Launch. Workspace (fp16 elems): WT 4M | q_up 8M | k_up 8M | vT 8M | ctx 8M
// | pmask 2MB. Total ~74 MB.
// ---------------------------------------------------------------------------
extern "C" void kernel_launch(void* const* d_in, const int* in_sizes, int n_in,
                              void* d_out, int out_size, void* d_ws, size_t ws_size,
                              hipStream_t stream) {
  const float* key   = (const float*)d_in[0];
  const float* value = (const float*)d_in[1];
  const float* query = (const float*)d_in[2];
  const int*   mask  = (const int*)d_in[3];     // bool -> int32 per harness
  const float* Wq = (const float*)d_in[4];
  const float* bq = (const float*)d_in[5];
  const float* Wk = (const float*)d_in[6];
  const float* bk = (const float*)d_in[7];
  const float* Wv = (const float*)d_in[8];
  const float* bv = (const float*)d_in[9];
  const float* Wo = (const float*)d_in[10];
  const float* bo = (const float*)d_in[11];

  _Float16* wsp = (_Float16*)d_ws;
  _Float16* WT   = wsp;
  _Float16* q_up = wsp + (size_t)4 * 1024 * 1024;
  _Float16* k_up = q_up + (size_t)8192 * 1024;
  _Float16* vT   = k_up + (size_t)8192 * 1024;
  _Float16* ctx  = vT + (size_t)8192 * 1024;
  unsigned int* pmask = (unsigned int*)(ctx + (size_t)8192 * 1024);

  maskpack<<<dim3(2048), 256, 0, stream>>>(mask, pmask);
  wconv<<<dim3(32, 32, 4), 256, 0, stream>>>(Wq, Wk, Wv, Wo, WT);
  gemm_k<0><<<dim3(64, 8), 256, 0, stream>>>(query, WT, bq, q_up);
  gemm_k<1><<<dim3(64, 8), 256, 0, stream>>>(key, WT + (size_t)1024 * 1024, bk, k_up);
  gemm_k<2><<<dim3(64, 8), 256, 0, stream>>>(value, WT + (size_t)2 * 1024 * 1024, bv, vT);
  attn_k<<<dim3(16, 64), 256, 0, stream>>>(q_up, k_up, vT, pmask, ctx);
  gemm_k<3><<<dim3(64, 8), 256, 0, stream>>>(ctx, WT + (size_t)3 * 1024 * 1024, bo, (float*)d_out);
}

// Round 4
// 342.953 us; speedup vs baseline: 1.7832x; 1.1695x over previous
//
#include <hip/hip_runtime.h>

typedef _Float16 half8 __attribute__((ext_vector_type(8)));
typedef _Float16 half4 __attribute__((ext_vector_type(4)));
typedef float floatx4 __attribute__((ext_vector_type(4)));

#define MFMA16(A,B,C) __builtin_amdgcn_mfma_f32_16x16x32_f16((A),(B),(C),0,0,0)

// Problem constants (B=4, S=2048, D=1024, H=16, DPH=64)

// ---------------------------------------------------------------------------
// K0: bit-pack the int32 bool mask [B,S,S] -> u32 words [B,S,S/32]
// ---------------------------------------------------------------------------
__global__ __launch_bounds__(256) void maskpack(
    const int* __restrict__ m, unsigned int* __restrict__ p)
{
  const int w = blockIdx.x * 256 + threadIdx.x;   // 524288 words total
  const int4* s = (const int4*)(m + (size_t)w * 32);
  unsigned int bits = 0;
#pragma unroll
  for (int j = 0; j < 8; ++j) {
    const int4 v = s[j];
    bits |= (v.x ? 1u : 0u) << (j * 4 + 0);
    bits |= (v.y ? 1u : 0u) << (j * 4 + 1);
    bits |= (v.z ? 1u : 0u) << (j * 4 + 2);
    bits |= (v.w ? 1u : 0u) << (j * 4 + 3);
  }
  p[w] = bits;
}

// ---------------------------------------------------------------------------
// K1: convert the 4 weight matrices fp32 [k][n] -> fp16 W^T [n][k]
// ---------------------------------------------------------------------------
__global__ __launch_bounds__(256) void wconv(
    const float* __restrict__ Wq, const float* __restrict__ Wk,
    const float* __restrict__ Wv, const float* __restrict__ Wo,
    _Float16* __restrict__ dst)
{
  const float* W = (blockIdx.z == 0) ? Wq : (blockIdx.z == 1) ? Wk
                  : (blockIdx.z == 2) ? Wv : Wo;
  _Float16* WT = dst + (size_t)blockIdx.z * 1024 * 1024;
  __shared__ float t[32][33];
  const int tx = threadIdx.x & 31;
  const int ty = threadIdx.x >> 5;
  const int k0 = blockIdx.x * 32, n0 = blockIdx.y * 32;
#pragma unroll
  for (int j = 0; j < 4; ++j)
    t[ty + j * 8][tx] = W[(size_t)(k0 + ty + j * 8) * 1024 + n0 + tx];
  __syncthreads();
#pragma unroll
  for (int j = 0; j < 4; ++j)
    WT[(size_t)(n0 + ty + j * 8) * 1024 + k0 + tx] = (_Float16)t[tx][ty + j * 8];
}

// ---------------------------------------------------------------------------
// K2/K4: GEMM C[8192,1024] = A[8192,1024] @ W + bias, fp16 MFMA, fp32 accum.
// OP 0: A=query fp32, out = half q_up [B,H,S,64], (acc+bias)*0.125*log2(e)
// OP 1: A=key   fp32, out = half k_up [B,H,S,64]
// OP 2: A=value fp32, out = half vT   [B,H,64,S]  (transposed per head)
// OP 3: A=ctx  fp16,  out = float d_out [8192,1024]
// ---------------------------------------------------------------------------
template <int OP>
__global__ __launch_bounds__(256) void gemm_k(
    const void* __restrict__ Ap, const _Float16* __restrict__ BT,
    const float* __restrict__ bias, void* __restrict__ Cp)
{
  __shared__ __align__(16) _Float16 As[128 * 64];
  __shared__ __align__(16) _Float16 Bs[128 * 64];
  const int tid = threadIdx.x;
  const int lane = tid & 63;
  const int wv = tid >> 6;
  const int m0 = blockIdx.x * 128;
  const int n0 = blockIdx.y * 128;
  const int wr = (wv >> 1) * 64;
  const int wc = (wv & 1) * 64;

  floatx4 acc[4][4];
#pragma unroll
  for (int i = 0; i < 4; ++i)
#pragma unroll
    for (int j = 0; j < 4; ++j) acc[i][j] = (floatx4){0.f, 0.f, 0.f, 0.f};

  char* AsB = (char*)As;
  char* BsB = (char*)Bs;

  for (int ko = 0; ko < 1024; ko += 64) {
#pragma unroll
    for (int r = 0; r < 4; ++r) {
      const int idx = (r * 256 + tid) * 8;   // half index within 128x64 tile
      const int row = idx >> 6;
      const int colh = idx & 63;
      const int dstb = row * 128 + ((colh * 2) ^ ((row & 7) << 4));
      if (OP == 3) {
        const _Float16* s = (const _Float16*)Ap + (size_t)(m0 + row) * 1024 + ko + colh;
        *(half8*)(AsB + dstb) = *(const half8*)s;
      } else {
        const float* s = (const float*)Ap + (size_t)(m0 + row) * 1024 + ko + colh;
        floatx4 v0 = *(const floatx4*)s;
        floatx4 v1 = *(const floatx4*)(s + 4);
        half8 hv;
        hv[0] = (_Float16)v0[0]; hv[1] = (_Float16)v0[1];
        hv[2] = (_Float16)v0[2]; hv[3] = (_Float16)v0[3];
        hv[4] = (_Float16)v1[0]; hv[5] = (_Float16)v1[1];
        hv[6] = (_Float16)v1[2]; hv[7] = (_Float16)v1[3];
        *(half8*)(AsB + dstb) = hv;
      }
      const _Float16* bs = BT + (size_t)(n0 + row) * 1024 + ko + colh;
      *(half8*)(BsB + dstb) = *(const half8*)bs;
    }
    __syncthreads();
#pragma unroll
    for (int kk = 0; kk < 64; kk += 32) {
      half8 af[4], bf[4];
#pragma unroll
      for (int mi = 0; mi < 4; ++mi) {
        const int row = wr + mi * 16 + (lane & 15);
        const int cb = (kk + (lane >> 4) * 8) * 2;
        af[mi] = *(const half8*)(AsB + row * 128 + (cb ^ ((row & 7) << 4)));
      }
#pragma unroll
      for (int ni = 0; ni < 4; ++ni) {
        const int row = wc + ni * 16 + (lane & 15);
        const int cb = (kk + (lane >> 4) * 8) * 2;
        bf[ni] = *(const half8*)(BsB + row * 128 + (cb ^ ((row & 7) << 4)));
      }
#pragma unroll
      for (int mi = 0; mi < 4; ++mi)
#pragma unroll
        for (int ni = 0; ni < 4; ++ni)
          acc[mi][ni] = MFMA16(af[mi], bf[ni], acc[mi][ni]);
    }
    __syncthreads();
  }

  // Epilogue. C/D layout: col = lane&15, row = (lane>>4)*4 + i
#pragma unroll
  for (int ni = 0; ni < 4; ++ni) {
    const int nn = n0 + wc + ni * 16 + (lane & 15);
    const float bvv = bias[nn];
#pragma unroll
    for (int mi = 0; mi < 4; ++mi) {
      floatx4 c = acc[mi][ni];
#pragma unroll
      for (int i = 0; i < 4; ++i) {
        const int mm = m0 + wr + mi * 16 + (lane >> 4) * 4 + i;
        float val = c[i] + bvv;
        if (OP == 0) val *= 0.1803368801111204f;   // (1/8) * log2(e)
        if (OP == 0 || OP == 1) {
          _Float16* o = (_Float16*)Cp;
          const size_t off =
              ((size_t)((mm >> 11) * 16 + (nn >> 6)) * 2048 + (mm & 2047)) * 64 + (nn & 63);
          o[off] = (_Float16)val;
        } else if (OP == 2) {
          _Float16* o = (_Float16*)Cp;
          const size_t off =
              ((size_t)((mm >> 11) * 16 + (nn >> 6)) * 64 + (nn & 63)) * 2048 + (mm & 2047);
          o[off] = (_Float16)val;
        } else {
          float* o = (float*)Cp;
          o[(size_t)mm * 1024 + nn] = val;
        }
      }
    }
  }
}

// ---------------------------------------------------------------------------
// K3: flash attention, swapped operands, 4 q-tiles/wave (64 q-rows), KV=64.
// Grid: 512 blocks 1D, XCD-swizzled so each XCD owns 8 heads (K/V = 4MB = L2).
// Scores in log2 domain. Defer-max with THR=8. No barriers (wave-local LDS).
// ---------------------------------------------------------------------------
__global__ __launch_bounds__(256) void attn_k(
    const _Float16* __restrict__ q_up, const _Float16* __restrict__ k_up,
    const _Float16* __restrict__ vT, const unsigned int* __restrict__ pmask,
    _Float16* __restrict__ ctx)
{
  const int tid = threadIdx.x;
  const int lane = tid & 63;
  const int wv = tid >> 6;
  // XCD-locality swizzle (bijective over 512 = 8 xcd * 8 heads * 8 qchunks)
  const int bid = blockIdx.x;
  const int xcd = bid & 7;
  const int slot = bid >> 3;
  const int bh = xcd * 8 + (slot & 7);
  const int qc = slot >> 3;
  const int b = bh >> 4;
  const int h = bh & 15;
  const int q16 = lane & 15;
  const int g = lane >> 4;
  const int qw = qc * 256 + wv * 64;

  __shared__ __align__(16) _Float16 Plds[4][4][16 * 64];  // 32 KB

  const _Float16* qb = q_up + ((size_t)bh * 2048 + qw) * 64;
  const _Float16* kb = k_up + (size_t)bh * 2048 * 64;
  const _Float16* vb = vT + (size_t)bh * 64 * 2048;
  const unsigned int* mrow = pmask + ((size_t)b * 2048 + qw + q16) * 64;

  // Q B-frags (hoisted): col=q16, k = ks*32 + 8g + j
  half8 qf[4][2];
#pragma unroll
  for (int qt = 0; qt < 4; ++qt)
#pragma unroll
    for (int ks = 0; ks < 2; ++ks)
      qf[qt][ks] = *(const half8*)(qb + (size_t)(qt * 16 + q16) * 64 + ks * 32 + g * 8);

  floatx4 O[4][4];
#pragma unroll
  for (int qt = 0; qt < 4; ++qt)
#pragma unroll
    for (int dt = 0; dt < 4; ++dt) O[qt][dt] = (floatx4){0.f, 0.f, 0.f, 0.f};
  float mr[4] = {-__builtin_inff(), -__builtin_inff(), -__builtin_inff(), -__builtin_inff()};
  float lsum[4] = {0.f, 0.f, 0.f, 0.f};

  char* Pw = (char*)&Plds[wv][0][0];
  const int swz = (q16 & 7) << 4;

#pragma unroll 1
  for (int k0 = 0; k0 < 2048; k0 += 64) {
    // K A-frags: row=key16=q16, k = ks*32 + 8g + j
    half8 kf[4][2];
#pragma unroll
    for (int kt = 0; kt < 4; ++kt)
#pragma unroll
      for (int ks = 0; ks < 2; ++ks)
        kf[kt][ks] = *(const half8*)(kb + (size_t)(k0 + kt * 16 + q16) * 64 + ks * 32 + g * 8);
    // V^T A-frags: row=d16=q16, k = kb2*32 + 8g + j
    half8 vf[4][2];
#pragma unroll
    for (int dt = 0; dt < 4; ++dt)
#pragma unroll
      for (int kb2 = 0; kb2 < 2; ++kb2)
        vf[dt][kb2] = *(const half8*)(vb + (size_t)(dt * 16 + q16) * 2048 + k0 + kb2 * 32 + g * 8);
    // mask words: 2 per q-tile (keys k0..k0+63)
    uint2 mw[4];
#pragma unroll
    for (int qt = 0; qt < 4; ++qt)
      mw[qt] = *(const uint2*)(mrow + qt * 1024 + (k0 >> 5));

    // QK^T for all 4 q-tiles (independent chains)
    floatx4 s[4][4];
    __builtin_amdgcn_s_setprio(1);
#pragma unroll
    for (int qt = 0; qt < 4; ++qt)
#pragma unroll
      for (int kt = 0; kt < 4; ++kt) {
        floatx4 a0 = (floatx4){0.f, 0.f, 0.f, 0.f};
        a0 = MFMA16(kf[kt][0], qf[qt][0], a0);
        s[qt][kt] = MFMA16(kf[kt][1], qf[qt][1], a0);
      }
    __builtin_amdgcn_s_setprio(0);

    // softmax per q-tile (4 independent chains, log2 domain, defer-max)
#pragma unroll
    for (int qt = 0; qt < 4; ++qt) {
#pragma unroll
      for (int kt = 0; kt < 4; ++kt) {
        const unsigned int w =
            ((kt & 1) ? mw[qt].y : mw[qt].x) >> (((kt >> 1) == (kt & 1) ? 0 : 0) + (kt & 1) * 0);
        (void)w;
      }
      // mask: word = mw[qt].{x:keys 0-31, y:keys 32-63}; kt pairs per word
#pragma unroll
      for (int kt = 0; kt < 4; ++kt) {
        const unsigned int wd = (kt < 2) ? mw[qt].x : mw[qt].y;
        const unsigned int sh = wd >> ((kt & 1) * 16 + 4 * g);
#pragma unroll
        for (int r = 0; r < 4; ++r)
          if ((sh >> r) & 1u) s[qt][kt][r] = -1e30f;
      }
      float pm = s[qt][0][0];
#pragma unroll
      for (int kt = 0; kt < 4; ++kt)
#pragma unroll
        for (int r = 0; r < 4; ++r) pm = fmaxf(pm, s[qt][kt][r]);
      pm = fmaxf(pm, __shfl_xor(pm, 16));
      pm = fmaxf(pm, __shfl_xor(pm, 32));
      if (__any(pm > mr[qt] + 8.f)) {          // rescale only when max grows
        const float mn = fmaxf(mr[qt], pm);
        const float alpha = __builtin_amdgcn_exp2f(mr[qt] - mn);
        mr[qt] = mn;
        lsum[qt] *= alpha;
#pragma unroll
        for (int dt = 0; dt < 4; ++dt) O[qt][dt] *= alpha;
      }
      float rs = 0.f;
#pragma unroll
      for (int kt = 0; kt < 4; ++kt)
#pragma unroll
        for (int r = 0; r < 4; ++r) {
          const float e = __builtin_amdgcn_exp2f(s[qt][kt][r] - mr[qt]);
          s[qt][kt][r] = e;
          rs += e;
        }
      rs += __shfl_xor(rs, 16);
      rs += __shfl_xor(rs, 32);
      lsum[qt] += rs;
      // P -> LDS (fp16), row q16, keys 16kt+4g..+3, XOR-swizzled
      char* Pb = Pw + qt * 2048;
#pragma unroll
      for (int kt = 0; kt < 4; ++kt) {
        half4 w4;
        w4[0] = (_Float16)s[qt][kt][0]; w4[1] = (_Float16)s[qt][kt][1];
        w4[2] = (_Float16)s[qt][kt][2]; w4[3] = (_Float16)s[qt][kt][3];
        *(half4*)(Pb + q16 * 128 + ((32 * kt + 8 * g) ^ swz)) = w4;
      }
    }

    // PV: O^T += mfma(V^T, P), P read back key-contiguous
    __builtin_amdgcn_s_setprio(1);
#pragma unroll
    for (int qt = 0; qt < 4; ++qt) {
      char* Pb = Pw + qt * 2048;
      half8 pb[2];
#pragma unroll
      for (int kb2 = 0; kb2 < 2; ++kb2)
        pb[kb2] = *(const half8*)(Pb + q16 * 128 + ((64 * kb2 + 16 * g) ^ swz));
#pragma unroll
      for (int dt = 0; dt < 4; ++dt) {
        O[qt][dt] = MFMA16(vf[dt][0], pb[0], O[qt][dt]);
        O[qt][dt] = MFMA16(vf[dt][1], pb[1], O[qt][dt]);
      }
    }
    __builtin_amdgcn_s_setprio(0);
  }

  // Epilogue: O^T col=q16 (q), row = dt*16 + 4g + r (d). Normalize, 8B packs.
#pragma unroll
  for (int qt = 0; qt < 4; ++qt) {
    const float inv = 1.f / lsum[qt];
    const size_t rowb = ((size_t)(b * 2048 + qw + qt * 16 + q16)) * 1024 + h * 64;
#pragma unroll
    for (int dt = 0; dt < 4; ++dt) {
      half4 w4;
      w4[0] = (_Float16)(O[qt][dt][0] * inv);
      w4[1] = (_Float16)(O[qt][dt][1] * inv);
      w4[2] = (_Float16)(O[qt][dt][2] * inv);
      w4[3] = (_Float16)(O[qt][dt][3] * inv);
      *(half4*)(ctx + rowb + dt * 16 + 4 * g) = w4;
    }
  }
}

// ---------------------------------------------------------------------------
// Launch. Workspace (fp16 elems): WT 4M | q_up 8M | k_up 8M | vT 8M | ctx 8M
// | pmask 2MB. Total ~74 MB.
// ---------------------------------------------------------------------------
extern "C" void kernel_launch(void* const* d_in, const int* in_sizes, int n_in,
                              void* d_out, int out_size, void* d_ws, size_t ws_size,
                              hipStream_t stream) {
  const float* key   = (const float*)d_in[0];
  const float* value = (const float*)d_in[1];
  const float* query = (const float*)d_in[2];
  const int*   mask  = (const int*)d_in[3];     // bool -> int32 per harness
  const float* Wq = (const float*)d_in[4];
  const float* bq = (const float*)d_in[5];
  const float* Wk = (const float*)d_in[6];
  const float* bk = (const float*)d_in[7];
  const float* Wv = (const float*)d_in[8];
  const float* bv = (const float*)d_in[9];
  const float* Wo = (const float*)d_in[10];
  const float* bo = (const float*)d_in[11];

  _Float16* wsp = (_Float16*)d_ws;
  _Float16* WT   = wsp;
  _Float16* q_up = wsp + (size_t)4 * 1024 * 1024;
  _Float16* k_up = q_up + (size_t)8192 * 1024;
  _Float16* vT   = k_up + (size_t)8192 * 1024;
  _Float16* ctx  = vT + (size_t)8192 * 1024;
  unsigned int* pmask = (unsigned int*)(ctx + (size_t)8192 * 1024);

  maskpack<<<dim3(2048), 256, 0, stream>>>(mask, pmask);
  wconv<<<dim3(32, 32, 4), 256, 0, stream>>>(Wq, Wk, Wv, Wo, WT);
  gemm_k<0><<<dim3(64, 8), 256, 0, stream>>>(query, WT, bq, q_up);
  gemm_k<1><<<dim3(64, 8), 256, 0, stream>>>(key, WT + (size_t)1024 * 1024, bk, k_up);
  gemm_k<2><<<dim3(64, 8), 256, 0, stream>>>(value, WT + (size_t)2 * 1024 * 1024, bv, vT);
  attn_k<<<dim3(512), 256, 0, stream>>>(q_up, k_up, vT, pmask, ctx);
  gemm_k<3><<<dim3(64, 8), 256, 0, stream>>>(ctx, WT + (size_t)3 * 1024 * 1024, bo, (float*)d_out);
}

// Round 7
// 300.052 us; speedup vs baseline: 2.0382x; 1.1430x over previous
//
#include <hip/hip_runtime.h>

typedef _Float16 half8 __attribute__((ext_vector_type(8)));
typedef _Float16 half4 __attribute__((ext_vector_type(4)));
typedef float floatx4 __attribute__((ext_vector_type(4)));
typedef float floatx16 __attribute__((ext_vector_type(16)));

#define MFMA16(A,B,C) __builtin_amdgcn_mfma_f32_16x16x32_f16((A),(B),(C),0,0,0)
#define MFMA32(A,B,C) __builtin_amdgcn_mfma_f32_32x32x16_f16((A),(B),(C),0,0,0)

// Problem constants (B=4, S=2048, D=1024, H=16, DPH=64)

// ---------------------------------------------------------------------------
// K0: bit-pack the int32 bool mask [B,S,S] -> u32 words [B,S,S/32]
// ---------------------------------------------------------------------------
__global__ __launch_bounds__(256) void maskpack(
    const int* __restrict__ m, unsigned int* __restrict__ p)
{
  const int w = blockIdx.x * 256 + threadIdx.x;   // 524288 words total
  const int4* s = (const int4*)(m + (size_t)w * 32);
  unsigned int bits = 0;
#pragma unroll
  for (int j = 0; j < 8; ++j) {
    const int4 v = s[j];
    bits |= (v.x ? 1u : 0u) << (j * 4 + 0);
    bits |= (v.y ? 1u : 0u) << (j * 4 + 1);
    bits |= (v.z ? 1u : 0u) << (j * 4 + 2);
    bits |= (v.w ? 1u : 0u) << (j * 4 + 3);
  }
  p[w] = bits;
}

// ---------------------------------------------------------------------------
// K1: convert the 4 weight matrices fp32 [k][n] -> fp16 W^T [n][k]
// ---------------------------------------------------------------------------
__global__ __launch_bounds__(256) void wconv(
    const float* __restrict__ Wq, const float* __restrict__ Wk,
    const float* __restrict__ Wv, const float* __restrict__ Wo,
    _Float16* __restrict__ dst)
{
  const float* W = (blockIdx.z == 0) ? Wq : (blockIdx.z == 1) ? Wk
                  : (blockIdx.z == 2) ? Wv : Wo;
  _Float16* WT = dst + (size_t)blockIdx.z * 1024 * 1024;
  __shared__ float t[32][33];
  const int tx = threadIdx.x & 31;
  const int ty = threadIdx.x >> 5;
  const int k0 = blockIdx.x * 32, n0 = blockIdx.y * 32;
#pragma unroll
  for (int j = 0; j < 4; ++j)
    t[ty + j * 8][tx] = W[(size_t)(k0 + ty + j * 8) * 1024 + n0 + tx];
  __syncthreads();
#pragma unroll
  for (int j = 0; j < 4; ++j)
    WT[(size_t)(n0 + ty + j * 8) * 1024 + k0 + tx] = (_Float16)t[tx][ty + j * 8];
}

// ---------------------------------------------------------------------------
// K2/K4: GEMM C[8192,1024] = A[8192,1024] @ W + bias, fp16 MFMA, fp32 accum.
// OP 0: A=query fp32, out = half q_up [B,H,S,64], (acc+bias)*0.125*log2(e)
// OP 1: A=key   fp32, out = half k_up [B,H,S,64]
// OP 2: A=value fp32, out = half vT   [B,H,64,S]  (transposed per head)
// OP 3: A=ctx  fp16,  out = float d_out [8192,1024]
// ---------------------------------------------------------------------------
template <int OP>
__global__ __launch_bounds__(256) void gemm_k(
    const void* __restrict__ Ap, const _Float16* __restrict__ BT,
    const float* __restrict__ bias, void* __restrict__ Cp)
{
  __shared__ __align__(16) _Float16 As[128 * 64];
  __shared__ __align__(16) _Float16 Bs[128 * 64];
  const int tid = threadIdx.x;
  const int lane = tid & 63;
  const int wv = tid >> 6;
  const int m0 = blockIdx.x * 128;
  const int n0 = blockIdx.y * 128;
  const int wr = (wv >> 1) * 64;
  const int wc = (wv & 1) * 64;

  floatx4 acc[4][4];
#pragma unroll
  for (int i = 0; i < 4; ++i)
#pragma unroll
    for (int j = 0; j < 4; ++j) acc[i][j] = (floatx4){0.f, 0.f, 0.f, 0.f};

  char* AsB = (char*)As;
  char* BsB = (char*)Bs;

  for (int ko = 0; ko < 1024; ko += 64) {
#pragma unroll
    for (int r = 0; r < 4; ++r) {
      const int idx = (r * 256 + tid) * 8;   // half index within 128x64 tile
      const int row = idx >> 6;
      const int colh = idx & 63;
      const int dstb = row * 128 + ((colh * 2) ^ ((row & 7) << 4));
      if (OP == 3) {
        const _Float16* s = (const _Float16*)Ap + (size_t)(m0 + row) * 1024 + ko + colh;
        *(half8*)(AsB + dstb) = *(const half8*)s;
      } else {
        const float* s = (const float*)Ap + (size_t)(m0 + row) * 1024 + ko + colh;
        floatx4 v0 = *(const floatx4*)s;
        floatx4 v1 = *(const floatx4*)(s + 4);
        half8 hv;
        hv[0] = (_Float16)v0[0]; hv[1] = (_Float16)v0[1];
        hv[2] = (_Float16)v0[2]; hv[3] = (_Float16)v0[3];
        hv[4] = (_Float16)v1[0]; hv[5] = (_Float16)v1[1];
        hv[6] = (_Float16)v1[2]; hv[7] = (_Float16)v1[3];
        *(half8*)(AsB + dstb) = hv;
      }
      const _Float16* bs = BT + (size_t)(n0 + row) * 1024 + ko + colh;
      *(half8*)(BsB + dstb) = *(const half8*)bs;
    }
    __syncthreads();
#pragma unroll
    for (int kk = 0; kk < 64; kk += 32) {
      half8 af[4], bf[4];
#pragma unroll
      for (int mi = 0; mi < 4; ++mi) {
        const int row = wr + mi * 16 + (lane & 15);
        const int cb = (kk + (lane >> 4) * 8) * 2;
        af[mi] = *(const half8*)(AsB + row * 128 + (cb ^ ((row & 7) << 4)));
      }
#pragma unroll
      for (int ni = 0; ni < 4; ++ni) {
        const int row = wc + ni * 16 + (lane & 15);
        const int cb = (kk + (lane >> 4) * 8) * 2;
        bf[ni] = *(const half8*)(BsB + row * 128 + (cb ^ ((row & 7) << 4)));
      }
#pragma unroll
      for (int mi = 0; mi < 4; ++mi)
#pragma unroll
        for (int ni = 0; ni < 4; ++ni)
          acc[mi][ni] = MFMA16(af[mi], bf[ni], acc[mi][ni]);
    }
    __syncthreads();
  }

  // Epilogue. C/D layout: col = lane&15, row = (lane>>4)*4 + i
#pragma unroll
  for (int ni = 0; ni < 4; ++ni) {
    const int nn = n0 + wc + ni * 16 + (lane & 15);
    const float bvv = bias[nn];
#pragma unroll
    for (int mi = 0; mi < 4; ++mi) {
      floatx4 c = acc[mi][ni];
#pragma unroll
      for (int i = 0; i < 4; ++i) {
        const int mm = m0 + wr + mi * 16 + (lane >> 4) * 4 + i;
        float val = c[i] + bvv;
        if (OP == 0) val *= 0.1803368801111204f;   // (1/8) * log2(e)
        if (OP == 0 || OP == 1) {
          _Float16* o = (_Float16*)Cp;
          const size_t off =
              ((size_t)((mm >> 11) * 16 + (nn >> 6)) * 2048 + (mm & 2047)) * 64 + (nn & 63);
          o[off] = (_Float16)val;
        } else if (OP == 2) {
          _Float16* o = (_Float16*)Cp;
          const size_t off =
              ((size_t)((mm >> 11) * 16 + (nn >> 6)) * 64 + (nn & 63)) * 2048 + (mm & 2047);
          o[off] = (_Float16)val;
        } else {
          float* o = (float*)Cp;
          o[(size_t)mm * 1024 + nn] = val;
        }
      }
    }
  }
}

// ---------------------------------------------------------------------------
// K3: flash attention, 32x32x16 MFMA, in-register softmax, ZERO LDS.
// Grid 512 blocks, 4 waves; wave owns 64 q-rows (2 q-col tiles of 32).
// All cross-half traffic via __shfl_xor(.,32) (proven primitive).
// Scores in log2 domain (q pre-scaled by 0.125*log2e); defer-max THR=8.
// S^T = mfma32(A=K, B=Q): lane l (q=l&31, hi=l>>5), reg r holds score for
//   key = k0 + (r&3) + 8*(r>>2) + 4*hi.
// PV: O^T = mfma32(A=V^T, B=P); P B-frags (key-contig fp16 pairs) built by
//   exchanging the partner-needed pairs via 4 shfl_xor + hi-selects.
// ---------------------------------------------------------------------------
__global__ __launch_bounds__(256, 2) void attn_k(
    const _Float16* __restrict__ q_up, const _Float16* __restrict__ k_up,
    const _Float16* __restrict__ vT, const unsigned int* __restrict__ pmask,
    _Float16* __restrict__ ctx)
{
  const int tid = threadIdx.x;
  const int lane = tid & 63;
  const int wv = tid >> 6;
  // XCD-locality swizzle (bijective over 512 = 8 xcd * 8 heads * 8 qchunks)
  const int bid = blockIdx.x;
  const int xcd = bid & 7;
  const int slot = bid >> 3;
  const int bh = xcd * 8 + (slot & 7);
  const int qc = slot >> 3;
  const int b = bh >> 4;
  const int h = bh & 15;
  const int l31 = lane & 31;
  const int hi = lane >> 5;
  const int qw = qc * 256 + wv * 64;

  const _Float16* qb = q_up + ((size_t)bh * 2048 + qw) * 64;
  const _Float16* kb = k_up + (size_t)bh * 2048 * 64;
  const _Float16* vb = vT + (size_t)bh * 64 * 2048;
  const unsigned int* mroww = pmask + ((size_t)b * 2048 + qw + l31) * 64;

  // Q B-frags (hoisted): col=q=l31, k = kk*16 + hi*8 + j
  half8 qf[2][4];
#pragma unroll
  for (int qt = 0; qt < 2; ++qt)
#pragma unroll
    for (int kk = 0; kk < 4; ++kk)
      qf[qt][kk] = *(const half8*)(qb + (size_t)(qt * 32 + l31) * 64 + kk * 16 + hi * 8);

  floatx16 O[2][2];
#pragma unroll
  for (int qt = 0; qt < 2; ++qt)
#pragma unroll
    for (int dt = 0; dt < 2; ++dt)
#pragma unroll
      for (int r = 0; r < 16; ++r) O[qt][dt][r] = 0.f;
  float mr[2] = {-__builtin_inff(), -__builtin_inff()};
  float lsum[2] = {0.f, 0.f};

#pragma unroll 1
  for (int k0 = 0; k0 < 2048; k0 += 32) {
    // K A-frags: row=key=l31, k = kk*16 + hi*8 + j
    half8 kf[4];
#pragma unroll
    for (int kk = 0; kk < 4; ++kk)
      kf[kk] = *(const half8*)(kb + (size_t)(k0 + l31) * 64 + kk * 16 + hi * 8);
    // V^T A-frags: row=d=dt*32+l31, k(key) = kk2*16 + hi*8 + j
    half8 vf[2][2];
#pragma unroll
    for (int dt = 0; dt < 2; ++dt)
#pragma unroll
      for (int kk2 = 0; kk2 < 2; ++kk2)
        vf[dt][kk2] = *(const half8*)(vb + (size_t)(dt * 32 + l31) * 2048 + k0 + kk2 * 16 + hi * 8);
    // mask words (1 per q-tile; lanes l and l+32 share q -> same word)
    unsigned int mw[2];
    mw[0] = mroww[(k0 >> 5)];
    mw[1] = mroww[32 * 64 + (k0 >> 5)];

    // QK^T for both q-tiles (independent chains over 4 d-slices)
    floatx16 s[2];
    __builtin_amdgcn_s_setprio(1);
#pragma unroll
    for (int qt = 0; qt < 2; ++qt) {
      floatx16 a;
#pragma unroll
      for (int r = 0; r < 16; ++r) a[r] = 0.f;
      a = MFMA32(kf[0], qf[qt][0], a);
      a = MFMA32(kf[1], qf[qt][1], a);
      a = MFMA32(kf[2], qf[qt][2], a);
      s[qt] = MFMA32(kf[3], qf[qt][3], a);
    }
    __builtin_amdgcn_s_setprio(0);

#pragma unroll
    for (int qt = 0; qt < 2; ++qt) {
      // mask: bit (j + 8m + 4hi) of mw kills score r=4m+j
      const unsigned int mh = mw[qt] >> (4 * hi);
#pragma unroll
      for (int m = 0; m < 4; ++m) {
        const unsigned int bm = mh >> (8 * m);
#pragma unroll
        for (int j = 0; j < 4; ++j)
          s[qt][4 * m + j] = ((bm >> j) & 1u) ? -1e30f : s[qt][4 * m + j];
      }
      // row max: in-register tree + one cross-half shuffle
      float t0 = fmaxf(fmaxf(s[qt][0], s[qt][1]), fmaxf(s[qt][2], s[qt][3]));
      float t1 = fmaxf(fmaxf(s[qt][4], s[qt][5]), fmaxf(s[qt][6], s[qt][7]));
      float t2 = fmaxf(fmaxf(s[qt][8], s[qt][9]), fmaxf(s[qt][10], s[qt][11]));
      float t3 = fmaxf(fmaxf(s[qt][12], s[qt][13]), fmaxf(s[qt][14], s[qt][15]));
      float pm = fmaxf(fmaxf(t0, t1), fmaxf(t2, t3));
      pm = fmaxf(pm, __shfl_xor(pm, 32));
      if (__any(pm > mr[qt] + 8.f)) {          // rescale only when max grows
        const float mn = fmaxf(mr[qt], pm);
        const float alpha = __builtin_amdgcn_exp2f(mr[qt] - mn);
        mr[qt] = mn;
        lsum[qt] *= alpha;
        O[qt][0] *= alpha;
        O[qt][1] *= alpha;
      }
      // exp2 + row sum (tree + one shuffle)
      float e[16];
#pragma unroll
      for (int r = 0; r < 16; ++r) e[r] = __builtin_amdgcn_exp2f(s[qt][r] - mr[qt]);
      float u0 = (e[0] + e[1]) + (e[2] + e[3]);
      float u1 = (e[4] + e[5]) + (e[6] + e[7]);
      float u2 = (e[8] + e[9]) + (e[10] + e[11]);
      float u3 = (e[12] + e[13]) + (e[14] + e[15]);
      float rs = (u0 + u1) + (u2 + u3);
      lsum[qt] += rs + __shfl_xor(rs, 32);

      // P -> fp16 pairs. c0..c7 keys (per lane): {0,1} {2,3} {8,9} {10,11}
      // {16,17} {18,19} {24,25} {26,27}, all +4*hi.
      unsigned int c0 = __builtin_bit_cast(unsigned int, __builtin_amdgcn_cvt_pkrtz(e[0], e[1]));
      unsigned int c1 = __builtin_bit_cast(unsigned int, __builtin_amdgcn_cvt_pkrtz(e[2], e[3]));
      unsigned int c2 = __builtin_bit_cast(unsigned int, __builtin_amdgcn_cvt_pkrtz(e[4], e[5]));
      unsigned int c3 = __builtin_bit_cast(unsigned int, __builtin_amdgcn_cvt_pkrtz(e[6], e[7]));
      unsigned int c4 = __builtin_bit_cast(unsigned int, __builtin_amdgcn_cvt_pkrtz(e[8], e[9]));
      unsigned int c5 = __builtin_bit_cast(unsigned int, __builtin_amdgcn_cvt_pkrtz(e[10], e[11]));
      unsigned int c6 = __builtin_bit_cast(unsigned int, __builtin_amdgcn_cvt_pkrtz(e[12], e[13]));
      unsigned int c7 = __builtin_bit_cast(unsigned int, __builtin_amdgcn_cvt_pkrtz(e[14], e[15]));
      // Exchange partner-needed pairs: hi=0 sends c2,c3,c6,c7; hi=1 sends c0,c1,c4,c5.
      const unsigned int ra = __shfl_xor(hi ? c0 : c2, 32);
      const unsigned int rb = __shfl_xor(hi ? c1 : c3, 32);
      const unsigned int rc = __shfl_xor(hi ? c4 : c6, 32);
      const unsigned int rd = __shfl_xor(hi ? c5 : c7, 32);
      // B-frag k = hi*8 + j: hi=0 -> keys {0..7} / {16..23}; hi=1 -> {8..15} / {24..31}
      union { half8 v; unsigned int u[4]; } p0, p1;
      p0.u[0] = hi ? ra : c0;  p0.u[1] = hi ? rb : c1;
      p0.u[2] = hi ? c2 : ra;  p0.u[3] = hi ? c3 : rb;
      p1.u[0] = hi ? rc : c4;  p1.u[1] = hi ? rd : c5;
      p1.u[2] = hi ? c6 : rc;  p1.u[3] = hi ? c7 : rd;
      // PV
      __builtin_amdgcn_s_setprio(1);
#pragma unroll
      for (int dt = 0; dt < 2; ++dt) {
        O[qt][dt] = MFMA32(vf[dt][0], p0.v, O[qt][dt]);
        O[qt][dt] = MFMA32(vf[dt][1], p1.v, O[qt][dt]);
      }
      __builtin_amdgcn_s_setprio(0);
    }
  }

  // Epilogue: O^T col=q=l31, row d = dt*32 + 8m + 4hi + {0..3} (regs 4m..4m+3)
#pragma unroll
  for (int qt = 0; qt < 2; ++qt) {
    const float inv = 1.f / lsum[qt];
    const size_t rowb = ((size_t)(b * 2048 + qw + qt * 32 + l31)) * 1024 + h * 64;
#pragma unroll
    for (int dt = 0; dt < 2; ++dt) {
#pragma unroll
      for (int m = 0; m < 4; ++m) {
        half4 w4;
        w4[0] = (_Float16)(O[qt][dt][4 * m + 0] * inv);
        w4[1] = (_Float16)(O[qt][dt][4 * m + 1] * inv);
        w4[2] = (_Float16)(O[qt][dt][4 * m + 2] * inv);
        w4[3] = (_Float16)(O[qt][dt][4 * m + 3] * inv);
        *(half4*)(ctx + rowb + dt * 32 + 8 * m + 4 * hi) = w4;
      }
    }
  }
}

// ---------------------------------------------------------------------------
// Launch. Workspace (fp16 elems): WT 4M | q_up 8M | k_up 8M | vT 8M | ctx 8M
// | pmask 2MB. Total ~74 MB.
// ---------------------------------------------------------------------------
extern "C" void kernel_launch(void* const* d_in, const int* in_sizes, int n_in,
                              void* d_out, int out_size, void* d_ws, size_t ws_size,
                              hipStream_t stream) {
  const float* key   = (const float*)d_in[0];
  const float* value = (const float*)d_in[1];
  const float* query = (const float*)d_in[2];
  const int*   mask  = (const int*)d_in[3];     // bool -> int32 per harness
  const float* Wq = (const float*)d_in[4];
  const float* bq = (const float*)d_in[5];
  const float* Wk = (const float*)d_in[6];
  const float* bk = (const float*)d_in[7];
  const float* Wv = (const float*)d_in[8];
  const float* bv = (const float*)d_in[9];
  const float* Wo = (const float*)d_in[10];
  const float* bo = (const float*)d_in[11];

  _Float16* wsp = (_Float16*)d_ws;
  _Float16* WT   = wsp;
  _Float16* q_up = wsp + (size_t)4 * 1024 * 1024;
  _Float16* k_up = q_up + (size_t)8192 * 1024;
  _Float16* vT   = k_up + (size_t)8192 * 1024;
  _Float16* ctx  = vT + (size_t)8192 * 1024;
  unsigned int* pmask = (unsigned int*)(ctx + (size_t)8192 * 1024);

  maskpack<<<dim3(2048), 256, 0, stream>>>(mask, pmask);
  wconv<<<dim3(32, 32, 4), 256, 0, stream>>>(Wq, Wk, Wv, Wo, WT);
  gemm_k<0><<<dim3(64, 8), 256, 0, stream>>>(query, WT, bq, q_up);
  gemm_k<1><<<dim3(64, 8), 256, 0, stream>>>(key, WT + (size_t)1024 * 1024, bk, k_up);
  gemm_k<2><<<dim3(64, 8), 256, 0, stream>>>(value, WT + (size_t)2 * 1024 * 1024, bv, vT);
  attn_k<<<dim3(512), 256, 0, stream>>>(q_up, k_up, vT, pmask, ctx);
  gemm_k<3><<<dim3(64, 8), 256, 0, stream>>>(ctx, WT + (size_t)3 * 1024 * 1024, bo, (float*)d_out);
}